// Round 1
// baseline (194.646 us; speedup 1.0000x reference)
//
#include <hip/hip_runtime.h>

constexpr int S   = 256;
constexpr int NL  = 17;
constexpr int L   = 19;   // start = 17, end = 18
constexpr int WPB = 2;    // waves per block
constexpr int NB  = 1536; // persistent blocks: 6 per CU x 256 CUs -> 3 waves/SIMD
constexpr int CAP = 16384;

// work queue: sequence indices sorted by descending length, plus grab counter
__device__ int g_sorted[CAP];
__device__ int g_counter;

// Counting sort of sequence indices by descending length (keys 256-len in [0,255]).
// Single block; also seeds g_counter with the number of statically-assigned jobs.
__global__ __launch_bounds__(1024)
void crf_prep(const int* __restrict__ lens, int B, int nwaves)
{
    __shared__ int hist[256];
    __shared__ int offs[256];
    const int tid = threadIdx.x;
    if (tid == 0) g_counter = nwaves;
    if (B > CAP) return;              // identity order fallback (uniform exit)
    if (tid < 256) hist[tid] = 0;
    __syncthreads();
    for (int b = tid; b < B; b += 1024) {
        int k = 256 - lens[b];
        k = k < 0 ? 0 : (k > 255 ? 255 : k);
        atomicAdd(&hist[k], 1);
    }
    __syncthreads();
    int cnt = 0;
    if (tid < 256) cnt = hist[tid];
    // Hillis-Steele inclusive scan over 256 bins (barriers are block-uniform)
    for (int d = 1; d < 256; d <<= 1) {
        int v = 0;
        if (tid < 256) { v = hist[tid]; if (tid >= d) v += hist[tid - d]; }
        __syncthreads();
        if (tid < 256) hist[tid] = v;
        __syncthreads();
    }
    if (tid < 256) offs[tid] = hist[tid] - cnt;   // exclusive prefix
    __syncthreads();
    for (int b = tid; b < B; b += 1024) {
        int k = 256 - lens[b];
        k = k < 0 ? 0 : (k > 255 ? 255 : k);
        int pos = atomicAdd(&offs[k], 1);
        g_sorted[pos] = b;
    }
}

// One wave per sequence-job; persistent waves pull jobs longest-first.
// Half 0: fwd Z <- E (el o Z), Z0 = E[:,start], tokens [0,mid). Half 1: bwd
// V <- E^T (el o V), V0 = E[end,:], tokens (mid,len-1] walking down, plus a
// final elementwise el_mid. Combine P = sum Z*(el_mid o V). Gold path score
// computed post-loop by all 64 lanes. Probability domain, per-4-step max
// renorm, depth-8 prefetch.
// NOTE: no s_waitcnt between ds_write and ds_read — DS ops from one wave are
// processed in order by the LDS pipe; only a compiler barrier pins the order.
__global__ __launch_bounds__(64 * WPB)
void crf_fwd(const float* __restrict__ logits,
             const int*   __restrict__ labels,
             const int*   __restrict__ lens,
             const float* __restrict__ transition,
             float* __restrict__ out, int totalElemM1, int B, int useSort)
{
    __shared__ float Tsh[L * L];
    __shared__ __align__(16) float pbuf[WPB][2][2][32];  // [wave][half][parity]

    const int tid  = threadIdx.x;
    const int wave = tid >> 6;
    const int wtid = tid & 63;
    const int half = wtid >> 5;   // 0 = fwd, 1 = bwd
    const int lane = wtid & 31;

    for (int k = tid; k < L * L; k += 64 * WPB) Tsh[k] = transition[k];
    __syncthreads();   // once; nothing cross-wave afterwards

    const int  i    = lane;
    const bool act  = (i < L);
    const bool emit = (i < NL);
    const int  ic   = act ? i : 0;

    // loop-invariant: coefficient rows/cols and initial state (hoisted)
    float coef[L];
    #pragma unroll
    for (int j = 0; j < L; ++j)
        coef[j] = __expf(half ? Tsh[j * L + ic] : Tsh[ic * L + j]);

    const float p0 = act ? __expf(half ? Tsh[(L - 1) * L + ic]     // E[end, i]
                                       : Tsh[ic * L + (L - 2)])    // E[i, start]
                         : 0.0f;
    const int   stride = half ? -(8 * NL * 4) : (8 * NL * 4);
    const char* lgbase = (const char*)logits;

    // static first job (avoids the t=0 atomic burst), then dynamic grabs
    int idx = blockIdx.x * WPB + wave;

    while (idx < B) {
        const int b = useSort ? g_sorted[idx] : idx;

        const int len = lens[b];
        const int mid = len >> 1;            // fwd full steps
        const int nb  = len - 1 - mid;       // bwd full steps (mid-1 or mid)
        const int nup = half ? nb : mid;
        const int nsteps = (mid + 7) & ~7;   // mid >= nb always

        const int seqbase = b * (S * NL);

        float p = p0;
        float m = 0.0f;

        // ---- depth-8 prefetch: 32-bit byte offsets, per-lane clamps ----
        const int capHiF = 4 * min(seqbase + (S - 1) * NL + i, totalElemM1);
        const int capHi  = half ? 0x7ffffffc : capHiF;
        const int capLo  = half ? 4 * (seqbase + i) : 0;

        int   off[8];
        float lgbuf[8];
        #pragma unroll
        for (int u = 0; u < 8; ++u) {
            int tok = half ? (len - 1 - u) : u;
            tok = tok > 0 ? tok : 0;
            int o = 4 * (seqbase + tok * NL + i);
            o = min(o, capHiF);
            off[u] = o;
            lgbuf[u] = *(const float*)(lgbase + o);
        }

        for (int tb = 0; tb < nsteps; tb += 8) {
            #pragma unroll
            for (int u = 0; u < 8; ++u) {
                const int   t  = tb + u;
                const float lg = lgbuf[u];
                // advance pipeline
                int o = off[u] + stride;
                o = max(o, capLo);
                o = min(o, capHi);
                off[u] = o;
                lgbuf[u] = *(const float*)(lgbase + o);

                const bool upd = (t < nup);

                const float el = emit ? __expf(lg) : 0.0f;
                const float pe = p * el;

                float* pb = &pbuf[wave][half][u & 1][0];
                pb[i] = pe;                                   // all 32 lanes write
                asm volatile("" ::: "memory");
                const float4* q = (const float4*)pb;
                const float4 q0 = q[0], q1 = q[1], q2 = q[2], q3 = q[3], q4 = q[4];

                float a0 = q0.x * coef[0];
                float a1 = q0.y * coef[1];
                float a2 = q0.z * coef[2];
                float a3 = q0.w * coef[3];
                a0 = fmaf(q1.x, coef[4],  a0);
                a1 = fmaf(q1.y, coef[5],  a1);
                a2 = fmaf(q1.z, coef[6],  a2);
                a3 = fmaf(q1.w, coef[7],  a3);
                a0 = fmaf(q2.x, coef[8],  a0);
                a1 = fmaf(q2.y, coef[9],  a1);
                a2 = fmaf(q2.z, coef[10], a2);
                a3 = fmaf(q2.w, coef[11], a3);
                a0 = fmaf(q3.x, coef[12], a0);
                a1 = fmaf(q3.y, coef[13], a1);
                a2 = fmaf(q3.z, coef[14], a2);
                a3 = fmaf(q3.w, coef[15], a3);
                a0 = fmaf(q4.x, coef[16], a0);
                a1 = fmaf(q4.y, coef[17], a1);
                a2 = fmaf(q4.z, coef[18], a2);

                float pn = (a0 + a1) + (a2 + a3);

                if ((u & 3) == 3) {   // renorm every 4 steps
                    float m0 = fmaxf(fmaxf(q0.x, q0.y), fmaxf(q0.z, q0.w));
                    float m1 = fmaxf(fmaxf(q1.x, q1.y), fmaxf(q1.z, q1.w));
                    float m2 = fmaxf(fmaxf(q2.x, q2.y), fmaxf(q2.z, q2.w));
                    float m3 = fmaxf(fmaxf(q3.x, q3.y), fmaxf(q3.z, q3.w));
                    float m4 = fmaxf(fmaxf(q4.x, q4.y), q4.z);
                    float mx = fmaxf(fmaxf(m0, m1), fmaxf(fmaxf(m2, m3), m4));
                    pn *= __frcp_rn(mx);
                    m += upd ? __logf(mx) : 0.0f;
                }
                p = upd ? pn : p;
            }
        }

        // ---- bwd leftover: multiply by el of token `mid` (no matvec) ----
        {
            float lgf = 0.0f;
            if (half && emit) lgf = logits[(size_t)(seqbase + mid * NL + i)];
            if (half) p = emit ? p * __expf(lgf) : 0.0f;
        }

        // ---- combine: P = sum_i Z_i * Vp_i ----
        const float other = __shfl_xor(p, 32);
        float prod = act ? p * other : 0.0f;
        #pragma unroll
        for (int o = 16; o >= 1; o >>= 1) prod += __shfl_xor(prod, o, 32);
        const float mtot = m + __shfl_xor(m, 32);
        const float norm = mtot + __logf(prod);

        // ---- gold phase: all 64 lanes sweep tokens ----
        const int* labp = labels + b * S;
        float gsum = 0.0f;
        for (int c = 0; c < len; c += 64) {
            const int tok = c + wtid;
            if (tok < len) {
                const int lab = labp[tok];
                const int prv = (tok == 0) ? (L - 2) : labp[tok - 1];
                gsum += logits[(size_t)(seqbase + tok * NL + lab)] + Tsh[lab * L + prv];
            }
        }
        #pragma unroll
        for (int o = 32; o >= 1; o >>= 1) gsum += __shfl_xor(gsum, o);
        const float gold = gsum + Tsh[(L - 1) * L + labp[len - 1]];

        if (wtid == 0) out[b] = gold - norm;

        // ---- grab next job (test-then-RMW avoids drain-time atomic burst) ----
        if (wtid == 0) {
            int c = *(volatile int*)&g_counter;   // monotone; stale-low is safe
            idx = (c >= B) ? B : atomicAdd(&g_counter, 1);
        }
        idx = __shfl(idx, 0);
    }
}

extern "C" void kernel_launch(void* const* d_in, const int* in_sizes, int n_in,
                              void* d_out, int out_size, void* d_ws, size_t ws_size,
                              hipStream_t stream)
{
    (void)n_in; (void)out_size; (void)d_ws; (void)ws_size;
    const float* logits     = (const float*)d_in[0];
    const int*   labels     = (const int*)d_in[1];
    const int*   lens       = (const int*)d_in[2];
    const float* transition = (const float*)d_in[3];
    float*       out        = (float*)d_out;
    const int B = in_sizes[2];
    const int totalElemM1 = B * S * NL - 1;
    const int useSort = (B <= CAP) ? 1 : 0;
    const int nwaves  = NB * WPB;

    crf_prep<<<dim3(1), dim3(1024), 0, stream>>>(lens, B, nwaves);
    crf_fwd<<<dim3(NB), dim3(64 * WPB), 0, stream>>>(
        logits, labels, lens, transition, out, totalElemM1, B, useSort);
}

// Round 2
// 166.545 us; speedup vs baseline: 1.1687x; 1.1687x over previous
//
#include <hip/hip_runtime.h>

constexpr int S    = 256;
constexpr int NL   = 17;
constexpr int L    = 19;   // start = 17, end = 18
constexpr int CAPB = 16384;

typedef float v4 __attribute__((ext_vector_type(4), aligned(4)));

// per-sequence scratch: fwd state Z, bwd state V (pre el_mid), log-scale factors
__device__ float g_Z[CAPB * 17];
__device__ float g_V[CAPB * 17];
__device__ float g_mf[CAPB];
__device__ float g_mv[CAPB];

// BIOES transition mask (i = to-label, j = from-label, 0..16; 0=O, 1+4t+p,
// p: 0=B 1=I 2=E 3=S). 97 of 289 entries allowed; rest are exp(-10000)=0.
__host__ __device__ constexpr bool allowedTo(int i, int j) {
    const int pi = (i == 0) ? 4 : ((i - 1) & 3);
    const int pj = (j == 0) ? 4 : ((j - 1) & 3);
    const int ti = (i == 0) ? -1 : ((i - 1) >> 2);
    const int tj = (j == 0) ? -2 : ((j - 1) >> 2);
    const bool fromOES = (pj == 4) || (pj == 2) || (pj == 3);
    const bool toOBS   = (pi == 4) || (pi == 0) || (pi == 3);
    if (fromOES && toOBS) return true;
    if (((pj == 0) || (pj == 1)) && ((pi == 1) || (pi == 2)) && (ti == tj)) return true;
    return false;
}

// One step of the recurrence: consume token in CUR, prefetch token t+1 into NXT.
// All indexing compile-time constant (registers only). Lanes past nup compute
// garbage (positive, renormed) that is never stored.
#define STEP(T_, CUR, NXT, RN)                                              \
    {                                                                       \
        const int t_ = (T_);                                                \
        {                                                                   \
            const int o_ = tokoff(t_ + 1);                                  \
            const v4   l0 = *(const v4*)(base + o_);                        \
            const v4   l1 = *(const v4*)(base + o_ + 16);                   \
            const v4   l2 = *(const v4*)(base + o_ + 32);                   \
            const v4   l3 = *(const v4*)(base + o_ + 48);                   \
            const float l4 = *(const float*)(base + o_ + 64);               \
            NXT[0] = l0.x;  NXT[1] = l0.y;  NXT[2] = l0.z;  NXT[3] = l0.w;  \
            NXT[4] = l1.x;  NXT[5] = l1.y;  NXT[6] = l1.z;  NXT[7] = l1.w;  \
            NXT[8] = l2.x;  NXT[9] = l2.y;  NXT[10] = l2.z; NXT[11] = l2.w; \
            NXT[12] = l3.x; NXT[13] = l3.y; NXT[14] = l3.z; NXT[15] = l3.w; \
            NXT[16] = l4;                                                   \
        }                                                                   \
        float q[17];                                                        \
        _Pragma("unroll")                                                   \
        for (int j = 0; j < 17; ++j) q[j] = __expf(CUR[j]) * p[j];          \
        _Pragma("unroll")                                                   \
        for (int i = 0; i < 17; ++i) {                                      \
            float acc = 0.0f;                                               \
            bool  fst = true;                                               \
            _Pragma("unroll")                                               \
            for (int j = 0; j < 17; ++j) {                                  \
                const bool al = BWD ? allowedTo(j, i) : allowedTo(i, j);    \
                if (al) {                                                   \
                    acc = fst ? cf[i][j] * q[j]                             \
                              : fmaf(cf[i][j], q[j], acc);                  \
                    fst = false;                                            \
                }                                                           \
            }                                                               \
            p[i] = acc;                                                     \
        }                                                                   \
        if (RN) {                                                           \
            float mx = p[16];                                               \
            _Pragma("unroll")                                               \
            for (int i = 0; i < 16; i += 2)                                 \
                mx = fmaxf(mx, fmaxf(p[i], p[i + 1]));                      \
            const float r_ = __frcp_rn(mx);                                 \
            _Pragma("unroll")                                               \
            for (int i = 0; i < 17; ++i) p[i] *= r_;                        \
            m += __logf(mx);                                                \
        }                                                                   \
        if (t_ == nup - 1) {                                                \
            float* dst = SC + bc * 17;                                      \
            _Pragma("unroll")                                               \
            for (int i = 0; i < 17; ++i) dst[i] = p[i];                     \
            SM[bc] = m;                                                     \
        }                                                                   \
    }

template <bool BWD>
__device__ __forceinline__ void chain(const float* __restrict__ logits,
                                      const int*   __restrict__ lens,
                                      const float* __restrict__ T,
                                      int B, int z)
{
    const int  lane  = threadIdx.x;
    const int  braw  = z * 64 + lane;
    const bool valid = braw < B;
    const int  bc    = valid ? braw : 0;

    const int len = lens[bc];
    const int mid = len >> 1;                    // fwd steps
    int nup = BWD ? (len - 1 - mid) : mid;       // per-lane step count
    if (!valid) nup = 0;

    // coefficients: fwd cf[i][j] = E[i][j]; bwd cf[i][j] = E[j][i] (transposed)
    float cf[17][17];
    #pragma unroll
    for (int i = 0; i < 17; ++i)
        #pragma unroll
        for (int j = 0; j < 17; ++j) {
            const bool al = BWD ? allowedTo(j, i) : allowedTo(i, j);
            if (al) cf[i][j] = __expf(BWD ? T[j * L + i] : T[i * L + j]);
        }

    // init state: fwd p0_i = E[i,start]; bwd v0_i = E[end,i]
    float p[17];
    #pragma unroll
    for (int i = 0; i < 17; ++i)
        p[i] = __expf(BWD ? T[(L - 1) * L + i] : T[i * L + (L - 2)]);

    float m = 0.0f;

    float* SC = BWD ? g_V : g_Z;
    float* SM = BWD ? g_mv : g_mf;

    // lanes with zero steps: state is the init vector
    if (nup == 0 && valid) {
        float* dst = SC + bc * 17;
        #pragma unroll
        for (int i = 0; i < 17; ++i) dst[i] = p[i];
        SM[bc] = 0.0f;
    }

    // wave-max step count (lanes past their nup run harmless garbage steps)
    int nmax = nup;
    #pragma unroll
    for (int o = 32; o >= 1; o >>= 1) nmax = max(nmax, __shfl_xor(nmax, o));

    const char* base = (const char*)logits;
    const int   sb4  = bc * (S * NL * 4);

    auto tokoff = [&](int t) -> int {
        int tok = BWD ? (len - 1 - t) : t;       // fwd tok <= 128 < S always
        if (BWD) tok = tok > 0 ? tok : 0;        // clamp: stays inside own seq
        return sb4 + tok * (NL * 4);
    };

    float curv[17], nxtv[17];
    {   // prologue: token for t = 0
        const int o_ = tokoff(0);
        const v4   l0 = *(const v4*)(base + o_);
        const v4   l1 = *(const v4*)(base + o_ + 16);
        const v4   l2 = *(const v4*)(base + o_ + 32);
        const v4   l3 = *(const v4*)(base + o_ + 48);
        const float l4 = *(const float*)(base + o_ + 64);
        curv[0] = l0.x;  curv[1] = l0.y;  curv[2] = l0.z;  curv[3] = l0.w;
        curv[4] = l1.x;  curv[5] = l1.y;  curv[6] = l1.z;  curv[7] = l1.w;
        curv[8] = l2.x;  curv[9] = l2.y;  curv[10] = l2.z; curv[11] = l2.w;
        curv[12] = l3.x; curv[13] = l3.y; curv[14] = l3.z; curv[15] = l3.w;
        curv[16] = l4;
    }

    for (int tb = 0; tb < nmax; tb += 2) {
        STEP(tb,     curv, nxtv, false)              // t even: never renorm
        STEP(tb + 1, nxtv, curv, ((tb & 3) == 2))    // renorm when t%4 == 3
    }
}

__global__ __launch_bounds__(64, 1)
void crf_chain(const float* __restrict__ logits, const int* __restrict__ lens,
               const float* __restrict__ T, int B, int nbh)
{
    if ((int)blockIdx.x < nbh) chain<false>(logits, lens, T, B, blockIdx.x);
    else                       chain<true >(logits, lens, T, B, blockIdx.x - nbh);
}

// Per sequence: P = sum_i Z_i * exp(logit_mid,i) * V_i ; norm = mf+mv+log P.
// Gold path score swept by all 64 lanes. One wave per sequence.
__global__ __launch_bounds__(64)
void crf_combine(const float* __restrict__ logits, const int* __restrict__ labels,
                 const int* __restrict__ lens, const float* __restrict__ T,
                 float* __restrict__ out, int B)
{
    const int b    = blockIdx.x;
    const int wtid = threadIdx.x;
    const int len  = lens[b];
    const int mid  = len >> 1;

    float prod = 0.0f;
    if (wtid < 17) {
        const float z  = g_Z[b * 17 + wtid];
        const float v  = g_V[b * 17 + wtid];
        const float lg = logits[(size_t)b * (S * NL) + mid * NL + wtid];
        prod = z * v * __expf(lg);
    }
    #pragma unroll
    for (int o = 32; o >= 1; o >>= 1) prod += __shfl_xor(prod, o);
    const float norm = g_mf[b] + g_mv[b] + __logf(prod);

    const int* labp = labels + b * S;
    float gsum = 0.0f;
    for (int c = 0; c < len; c += 64) {
        const int tok = c + wtid;
        if (tok < len) {
            const int lab = labp[tok];
            const int prv = (tok == 0) ? (L - 2) : labp[tok - 1];
            gsum += logits[(size_t)b * (S * NL) + tok * NL + lab] + T[lab * L + prv];
        }
    }
    #pragma unroll
    for (int o = 32; o >= 1; o >>= 1) gsum += __shfl_xor(gsum, o);
    const float gold = gsum + T[(L - 1) * L + labp[len - 1]];

    if (wtid == 0) out[b] = gold - norm;
}

extern "C" void kernel_launch(void* const* d_in, const int* in_sizes, int n_in,
                              void* d_out, int out_size, void* d_ws, size_t ws_size,
                              hipStream_t stream)
{
    (void)n_in; (void)out_size; (void)d_ws; (void)ws_size;
    const float* logits     = (const float*)d_in[0];
    const int*   labels     = (const int*)d_in[1];
    const int*   lens       = (const int*)d_in[2];
    const float* transition = (const float*)d_in[3];
    float*       out        = (float*)d_out;
    const int B   = in_sizes[2];
    const int NBH = (B + 63) / 64;

    crf_chain<<<dim3(2 * NBH), dim3(64), 0, stream>>>(logits, lens, transition, B, NBH);
    crf_combine<<<dim3(B), dim3(64), 0, stream>>>(logits, labels, lens, transition, out, B);
}